// Round 1
// baseline (1119.022 us; speedup 1.0000x reference)
//
#include <hip/hip_runtime.h>
#include <math.h>

#define N 6000
#define FIN 300
#define HID 128
#define NH 8
#define ALPHA 0.2f
#define NBR_CAP 512

// K0: build neighbor lists from dense adj (read adj exactly once)
__global__ void build_nbr(const float* __restrict__ adj,
                          unsigned short* __restrict__ nbr,
                          int* __restrict__ ncnt) {
    int n = blockIdx.x;
    int t = threadIdx.x;
    int lane = t & 63, w = t >> 6;
    __shared__ int wcnt[4];
    __shared__ int total;
    if (t == 0) total = 0;
    __syncthreads();
    const float* row = adj + (size_t)n * N;
    for (int base = 0; base < N; base += 256) {
        int m = base + t;
        bool p = (m < N) && (row[m] > 0.5f);
        unsigned long long mask = __ballot(p);
        int wc = __popcll(mask);
        if (lane == 0) wcnt[w] = wc;
        __syncthreads();
        int off = total;
        for (int i = 0; i < w; i++) off += wcnt[i];
        if (p) {
            int pos = __popcll(mask & ((1ull << lane) - 1ull));
            int idx = off + pos;
            if (idx < NBR_CAP) nbr[(size_t)n * NBR_CAP + idx] = (unsigned short)m;
        }
        __syncthreads();
        if (t == 0) total += wcnt[0] + wcnt[1] + wcnt[2] + wcnt[3];
        __syncthreads();
    }
    if (t == 0) ncnt[n] = total < NBR_CAP ? total : NBR_CAP;
}

// K1: Wh[h][n][o] = sum_f x[n][f] * W_heads[h][f][o]
__global__ void gemm_wh(const float* __restrict__ x,
                        const float* __restrict__ W,
                        float* __restrict__ Wh) {
    int h = blockIdx.y;
    int n0 = blockIdx.x * 64;
    __shared__ float xs[64][13];
    __shared__ float bs[12][128];
    int t = threadIdx.x;
    int tx = t & 31, ty = t >> 5;
    float acc[8][4] = {};
    for (int k0 = 0; k0 < FIN; k0 += 12) {
        for (int i = t; i < 64 * 12; i += 256) {
            int r = i / 12, c = i - r * 12;
            int n = n0 + r;
            xs[r][c] = (n < N) ? x[(size_t)n * FIN + k0 + c] : 0.f;
        }
        for (int i = t; i < 12 * 128; i += 256) {
            int r = i >> 7, c = i & 127;
            bs[r][c] = W[((size_t)h * FIN + (k0 + r)) * HID + c];
        }
        __syncthreads();
#pragma unroll
        for (int kk = 0; kk < 12; kk++) {
            float b[4];
#pragma unroll
            for (int j = 0; j < 4; j++) b[j] = bs[kk][tx * 4 + j];
#pragma unroll
            for (int i = 0; i < 8; i++) {
                float a = xs[ty * 8 + i][kk];
#pragma unroll
                for (int j = 0; j < 4; j++) acc[i][j] += a * b[j];
            }
        }
        __syncthreads();
    }
    for (int i = 0; i < 8; i++) {
        int n = n0 + ty * 8 + i;
        if (n < N) {
            float* o = Wh + ((size_t)h * N + n) * HID + tx * 4;
#pragma unroll
            for (int j = 0; j < 4; j++) o[j] = acc[i][j];
        }
    }
}

// K2: f1/f2 per (h,n); one wave per pair
__global__ void calc_f(const float* __restrict__ Wh,
                       const float* __restrict__ a_heads,
                       float* __restrict__ f1, float* __restrict__ f2) {
    int t = threadIdx.x, lane = t & 63, w = t >> 6;
    int pid = blockIdx.x * 4 + w;
    int h = pid / N, n = pid - h * N;
    const float* r = Wh + ((size_t)h * N + n) * HID;
    const float* a = a_heads + (size_t)h * 2 * HID;
    float v0 = r[lane], v1 = r[64 + lane];
    float s1 = v0 * a[lane] + v1 * a[64 + lane];
    float s2 = v0 * a[128 + lane] + v1 * a[192 + lane];
    for (int d = 32; d; d >>= 1) { s1 += __shfl_xor(s1, d); s2 += __shfl_xor(s2, d); }
    if (lane == 0) { f1[h * N + n] = s1; f2[h * N + n] = s2; }
}

// K3: layer-1 fused masked-softmax + PV (sparse)
__global__ void gat1(const float* __restrict__ Wh,
                     const float* __restrict__ f1, const float* __restrict__ f2,
                     const unsigned short* __restrict__ nbr,
                     const int* __restrict__ ncnt,
                     float* __restrict__ hcat) {
    int n = blockIdx.x;
    int t = threadIdx.x;
    int h0 = t >> 6, op = t & 63;
    int cnt = ncnt[n];
    const unsigned short* lst = nbr + (size_t)n * NBR_CAP;
    __shared__ float wl[256 * 8];
    __shared__ int   ml[256];
    __shared__ float sumw_s[8];

    float f1c[8];
#pragma unroll
    for (int h = 0; h < 8; h++) f1c[h] = f1[h * N + n];

    float2 acc0 = {0.f, 0.f}, acc1 = {0.f, 0.f};
    float sw0 = 0.f, sw1 = 0.f;

    for (int b0 = 0; b0 < cnt; b0 += 256) {
        int nb = min(256, cnt - b0);
        if (t < nb) {
            int m = lst[b0 + t];
            ml[t] = m;
#pragma unroll
            for (int h = 0; h < 8; h++) {
                float z = f1c[h] + f2[h * N + m];
                z = (z >= 0.f) ? z : ALPHA * z;
                wl[t * 8 + h] = __expf(z);
            }
        }
        __syncthreads();
#pragma unroll 4
        for (int j = 0; j < nb; j++) {
            int m = ml[j];
            float wA = wl[j * 8 + h0];
            float wB = wl[j * 8 + h0 + 4];
            const float2 v0 = *(const float2*)(Wh + ((size_t)h0 * N + m) * HID + 2 * op);
            const float2 v1 = *(const float2*)(Wh + ((size_t)(h0 + 4) * N + m) * HID + 2 * op);
            acc0.x += wA * v0.x; acc0.y += wA * v0.y;
            acc1.x += wB * v1.x; acc1.y += wB * v1.y;
            sw0 += wA; sw1 += wB;
        }
        __syncthreads();
    }
    if (op == 0) { sumw_s[h0] = sw0; sumw_s[h0 + 4] = sw1; }
    __syncthreads();
    float inv0 = 1.f / sumw_s[h0];
    float inv1 = 1.f / sumw_s[h0 + 4];
    float r0x = acc0.x * inv0, r0y = acc0.y * inv0;
    float r1x = acc1.x * inv1, r1y = acc1.y * inv1;
    r0x = (r0x > 0.f) ? r0x : expm1f(r0x);
    r0y = (r0y > 0.f) ? r0y : expm1f(r0y);
    r1x = (r1x > 0.f) ? r1x : expm1f(r1x);
    r1y = (r1y > 0.f) ? r1y : expm1f(r1y);
    float* o0 = hcat + (size_t)n * (NH * HID) + h0 * HID + 2 * op;
    float* o1 = hcat + (size_t)n * (NH * HID) + (h0 + 4) * HID + 2 * op;
    *(float2*)o0 = make_float2(r0x, r0y);
    *(float2*)o1 = make_float2(r1x, r1y);
}

// K4: Wh2 = hcat(6000x1024) @ W_out(1024x128)
__global__ void gemm_out(const float* __restrict__ hcat,
                         const float* __restrict__ W_out,
                         float* __restrict__ Wh2) {
    int n0 = blockIdx.x * 64;
    __shared__ float xs[64][17];
    __shared__ float bs[16][128];
    int t = threadIdx.x;
    int tx = t & 31, ty = t >> 5;
    float acc[8][4] = {};
    for (int k0 = 0; k0 < 1024; k0 += 16) {
        for (int i = t; i < 64 * 16; i += 256) {
            int r = i >> 4, c = i & 15;
            int n = n0 + r;
            xs[r][c] = (n < N) ? hcat[(size_t)n * 1024 + k0 + c] : 0.f;
        }
        for (int i = t; i < 16 * 128; i += 256) {
            int r = i >> 7, c = i & 127;
            bs[r][c] = W_out[(size_t)(k0 + r) * HID + c];
        }
        __syncthreads();
#pragma unroll
        for (int kk = 0; kk < 16; kk++) {
            float b[4];
#pragma unroll
            for (int j = 0; j < 4; j++) b[j] = bs[kk][tx * 4 + j];
#pragma unroll
            for (int i = 0; i < 8; i++) {
                float a = xs[ty * 8 + i][kk];
#pragma unroll
                for (int j = 0; j < 4; j++) acc[i][j] += a * b[j];
            }
        }
        __syncthreads();
    }
    for (int i = 0; i < 8; i++) {
        int n = n0 + ty * 8 + i;
        if (n < N) {
#pragma unroll
            for (int j = 0; j < 4; j++)
                Wh2[(size_t)n * HID + tx * 4 + j] = acc[i][j];
        }
    }
}

// K5: g1/g2
__global__ void calc_g(const float* __restrict__ Wh2,
                       const float* __restrict__ a_out,
                       float* __restrict__ g1, float* __restrict__ g2) {
    int t = threadIdx.x, lane = t & 63, w = t >> 6;
    int n = blockIdx.x * 4 + w;
    const float* r = Wh2 + (size_t)n * HID;
    float v0 = r[lane], v1 = r[64 + lane];
    float s1 = v0 * a_out[lane] + v1 * a_out[64 + lane];
    float s2 = v0 * a_out[128 + lane] + v1 * a_out[192 + lane];
    for (int d = 32; d; d >>= 1) { s1 += __shfl_xor(s1, d); s2 += __shfl_xor(s2, d); }
    if (lane == 0) { g1[n] = s1; g2[n] = s2; }
}

// K6: layer-2 fused masked-softmax + PV (sparse)
__global__ void gat2(const float* __restrict__ Wh2,
                     const float* __restrict__ g1, const float* __restrict__ g2,
                     const unsigned short* __restrict__ nbr,
                     const int* __restrict__ ncnt,
                     float* __restrict__ out) {
    int n = blockIdx.x, t = threadIdx.x;
    int s = t >> 6, op = t & 63;
    int cnt = ncnt[n];
    const unsigned short* lst = nbr + (size_t)n * NBR_CAP;
    __shared__ float wl[256];
    __shared__ int   ml[256];
    __shared__ float2 accl[4][64];
    __shared__ float swl[4];
    float g1c = g1[n];
    float2 acc = {0.f, 0.f};
    float sw = 0.f;
    for (int b0 = 0; b0 < cnt; b0 += 256) {
        int nb = min(256, cnt - b0);
        if (t < nb) {
            int m = lst[b0 + t];
            ml[t] = m;
            float z = g1c + g2[m];
            z = (z >= 0.f) ? z : ALPHA * z;
            wl[t] = __expf(z);
        }
        __syncthreads();
        for (int j = s; j < nb; j += 4) {
            int m = ml[j];
            float wj = wl[j];
            const float2 v = *(const float2*)(Wh2 + (size_t)m * HID + 2 * op);
            acc.x += wj * v.x; acc.y += wj * v.y;
            sw += wj;
        }
        __syncthreads();
    }
    accl[s][op] = acc;
    if (op == 0) swl[s] = sw;
    __syncthreads();
    if (t < 64) {
        float2 r0 = accl[0][t], r1 = accl[1][t], r2 = accl[2][t], r3 = accl[3][t];
        float rx = r0.x + r1.x + r2.x + r3.x;
        float ry = r0.y + r1.y + r2.y + r3.y;
        float inv = 1.f / (swl[0] + swl[1] + swl[2] + swl[3]);
        *(float2*)(out + (size_t)n * HID + 2 * t) = make_float2(rx * inv, ry * inv);
    }
}

extern "C" void kernel_launch(void* const* d_in, const int* in_sizes, int n_in,
                              void* d_out, int out_size, void* d_ws, size_t ws_size,
                              hipStream_t stream) {
    const float* x       = (const float*)d_in[0];
    const float* adj     = (const float*)d_in[1];
    const float* W_heads = (const float*)d_in[2];
    const float* a_heads = (const float*)d_in[3];
    const float* W_out   = (const float*)d_in[4];
    const float* a_out   = (const float*)d_in[5];
    float* out = (float*)d_out;

    char* wsb = (char*)d_ws;
    size_t off = 0;
    auto alloc = [&](size_t bytes) {
        void* p = wsb + off;
        off += (bytes + 255) & ~(size_t)255;
        return p;
    };
    float* Wh   = (float*)alloc(sizeof(float) * (size_t)NH * N * HID);
    float* hcat = (float*)alloc(sizeof(float) * (size_t)N * NH * HID);
    float* Wh2  = (float*)alloc(sizeof(float) * (size_t)N * HID);
    float* f1   = (float*)alloc(sizeof(float) * (size_t)NH * N);
    float* f2   = (float*)alloc(sizeof(float) * (size_t)NH * N);
    float* g1   = (float*)alloc(sizeof(float) * (size_t)N);
    float* g2   = (float*)alloc(sizeof(float) * (size_t)N);
    unsigned short* nbr = (unsigned short*)alloc(sizeof(unsigned short) * (size_t)N * NBR_CAP);
    int* ncnt = (int*)alloc(sizeof(int) * (size_t)N);

    hipLaunchKernelGGL(build_nbr, dim3(N), dim3(256), 0, stream, adj, nbr, ncnt);
    hipLaunchKernelGGL(gemm_wh, dim3((N + 63) / 64, NH), dim3(256), 0, stream, x, W_heads, Wh);
    hipLaunchKernelGGL(calc_f, dim3(NH * N / 4), dim3(256), 0, stream, Wh, a_heads, f1, f2);
    hipLaunchKernelGGL(gat1, dim3(N), dim3(256), 0, stream, Wh, f1, f2, nbr, ncnt, hcat);
    hipLaunchKernelGGL(gemm_out, dim3((N + 63) / 64), dim3(256), 0, stream, hcat, W_out, Wh2);
    hipLaunchKernelGGL(calc_g, dim3(N / 4), dim3(256), 0, stream, Wh2, a_out, g1, g2);
    hipLaunchKernelGGL(gat2, dim3(N), dim3(256), 0, stream, Wh2, g1, g2, nbr, ncnt, out);
}

// Round 2
// 671.489 us; speedup vs baseline: 1.6665x; 1.6665x over previous
//
#include <hip/hip_runtime.h>
#include <math.h>

#define N 6000
#define FIN 300
#define HID 128
#define NH 8
#define ALPHA 0.2f
#define NBR_CAP 512

// K0: build neighbor lists from dense adj (read adj exactly once)
__global__ void build_nbr(const float* __restrict__ adj,
                          unsigned short* __restrict__ nbr,
                          int* __restrict__ ncnt) {
    int n = blockIdx.x;
    int t = threadIdx.x;
    int lane = t & 63, w = t >> 6;
    __shared__ int wcnt[4];
    __shared__ int total;
    if (t == 0) total = 0;
    __syncthreads();
    const float* row = adj + (size_t)n * N;
    for (int base = 0; base < N; base += 256) {
        int m = base + t;
        bool p = (m < N) && (row[m] > 0.5f);
        unsigned long long mask = __ballot(p);
        int wc = __popcll(mask);
        if (lane == 0) wcnt[w] = wc;
        __syncthreads();
        int off = total;
        for (int i = 0; i < w; i++) off += wcnt[i];
        if (p) {
            int pos = __popcll(mask & ((1ull << lane) - 1ull));
            int idx = off + pos;
            if (idx < NBR_CAP) nbr[(size_t)n * NBR_CAP + idx] = (unsigned short)m;
        }
        __syncthreads();
        if (t == 0) total += wcnt[0] + wcnt[1] + wcnt[2] + wcnt[3];
        __syncthreads();
    }
    if (t == 0) ncnt[n] = total < NBR_CAP ? total : NBR_CAP;
}

// K1: Wh[h][n][o] = sum_f x[n][f] * W_heads[h][f][o]
__global__ void gemm_wh(const float* __restrict__ x,
                        const float* __restrict__ W,
                        float* __restrict__ Wh) {
    int h = blockIdx.y;
    int n0 = blockIdx.x * 64;
    __shared__ float xs[64][13];
    __shared__ float bs[12][128];
    int t = threadIdx.x;
    int tx = t & 31, ty = t >> 5;
    float acc[8][4] = {};
    for (int k0 = 0; k0 < FIN; k0 += 12) {
        for (int i = t; i < 64 * 12; i += 256) {
            int r = i / 12, c = i - r * 12;
            int n = n0 + r;
            xs[r][c] = (n < N) ? x[(size_t)n * FIN + k0 + c] : 0.f;
        }
        for (int i = t; i < 12 * 128; i += 256) {
            int r = i >> 7, c = i & 127;
            bs[r][c] = W[((size_t)h * FIN + (k0 + r)) * HID + c];
        }
        __syncthreads();
#pragma unroll
        for (int kk = 0; kk < 12; kk++) {
            float b[4];
#pragma unroll
            for (int j = 0; j < 4; j++) b[j] = bs[kk][tx * 4 + j];
#pragma unroll
            for (int i = 0; i < 8; i++) {
                float a = xs[ty * 8 + i][kk];
#pragma unroll
                for (int j = 0; j < 4; j++) acc[i][j] += a * b[j];
            }
        }
        __syncthreads();
    }
    for (int i = 0; i < 8; i++) {
        int n = n0 + ty * 8 + i;
        if (n < N) {
            float* o = Wh + ((size_t)h * N + n) * HID + tx * 4;
#pragma unroll
            for (int j = 0; j < 4; j++) o[j] = acc[i][j];
        }
    }
}

// K2: f1/f2 per (h,n); one wave per pair
__global__ void calc_f(const float* __restrict__ Wh,
                       const float* __restrict__ a_heads,
                       float* __restrict__ f1, float* __restrict__ f2) {
    int t = threadIdx.x, lane = t & 63, w = t >> 6;
    int pid = blockIdx.x * 4 + w;
    int h = pid / N, n = pid - h * N;
    const float* r = Wh + ((size_t)h * N + n) * HID;
    const float* a = a_heads + (size_t)h * 2 * HID;
    float v0 = r[lane], v1 = r[64 + lane];
    float s1 = v0 * a[lane] + v1 * a[64 + lane];
    float s2 = v0 * a[128 + lane] + v1 * a[192 + lane];
    for (int d = 32; d; d >>= 1) { s1 += __shfl_xor(s1, d); s2 += __shfl_xor(s2, d); }
    if (lane == 0) { f1[h * N + n] = s1; f2[h * N + n] = s2; }
}

// K3: layer-1 fused masked-softmax + PV, per-head blocks, head-major order.
// Working set per head = Wh[h] = 3 MB -> fits per-XCD L2 (4 MB).
// 8 neighbor-streams x 32 lanes, float4 gather (16 B/lane).
__global__ void gat1(const float* __restrict__ Wh,
                     const float* __restrict__ f1, const float* __restrict__ f2,
                     const unsigned short* __restrict__ nbr,
                     const int* __restrict__ ncnt,
                     float* __restrict__ hcat) {
    int bid = blockIdx.x;
    int h = bid / N, n = bid - h * N;       // head-major: all n of head 0 first
    int t = threadIdx.x;
    int s = t >> 5, op = t & 31;
    int cnt = ncnt[n];
    const unsigned short* lst = nbr + (size_t)n * NBR_CAP;
    __shared__ float wl[NBR_CAP];
    __shared__ int   ml[NBR_CAP];
    __shared__ float4 accl[8][32];
    __shared__ float swl[8];

    float f1c = f1[h * N + n];
    for (int i = t; i < cnt; i += 256) {
        int m = lst[i];
        ml[i] = m;
        float z = f1c + f2[h * N + m];
        z = (z >= 0.f) ? z : ALPHA * z;
        wl[i] = __expf(z);
    }
    __syncthreads();

    const float* base = Wh + (size_t)h * N * HID;
    float4 acc = {0.f, 0.f, 0.f, 0.f};
    float sw = 0.f;
    for (int j = s; j < cnt; j += 8) {
        float wj = wl[j];
        const float4 v = *(const float4*)(base + (size_t)ml[j] * HID + 4 * op);
        acc.x += wj * v.x; acc.y += wj * v.y;
        acc.z += wj * v.z; acc.w += wj * v.w;
        sw += wj;
    }
    accl[s][op] = acc;
    if (op == 0) swl[s] = sw;
    __syncthreads();

    if (t < 32) {
        float4 r = accl[0][t];
#pragma unroll
        for (int k = 1; k < 8; k++) {
            float4 q = accl[k][t];
            r.x += q.x; r.y += q.y; r.z += q.z; r.w += q.w;
        }
        float swt = 0.f;
#pragma unroll
        for (int k = 0; k < 8; k++) swt += swl[k];
        float inv = 1.f / swt;
        r.x *= inv; r.y *= inv; r.z *= inv; r.w *= inv;
        r.x = (r.x > 0.f) ? r.x : expm1f(r.x);
        r.y = (r.y > 0.f) ? r.y : expm1f(r.y);
        r.z = (r.z > 0.f) ? r.z : expm1f(r.z);
        r.w = (r.w > 0.f) ? r.w : expm1f(r.w);
        *(float4*)(hcat + (size_t)n * (NH * HID) + h * HID + 4 * t) = r;
    }
}

// K4: Wh2 = hcat(6000x1024) @ W_out(1024x128)
__global__ void gemm_out(const float* __restrict__ hcat,
                         const float* __restrict__ W_out,
                         float* __restrict__ Wh2) {
    int n0 = blockIdx.x * 64;
    __shared__ float xs[64][17];
    __shared__ float bs[16][128];
    int t = threadIdx.x;
    int tx = t & 31, ty = t >> 5;
    float acc[8][4] = {};
    for (int k0 = 0; k0 < 1024; k0 += 16) {
        for (int i = t; i < 64 * 16; i += 256) {
            int r = i >> 4, c = i & 15;
            int n = n0 + r;
            xs[r][c] = (n < N) ? hcat[(size_t)n * 1024 + k0 + c] : 0.f;
        }
        for (int i = t; i < 16 * 128; i += 256) {
            int r = i >> 7, c = i & 127;
            bs[r][c] = W_out[(size_t)(k0 + r) * HID + c];
        }
        __syncthreads();
#pragma unroll
        for (int kk = 0; kk < 16; kk++) {
            float b[4];
#pragma unroll
            for (int j = 0; j < 4; j++) b[j] = bs[kk][tx * 4 + j];
#pragma unroll
            for (int i = 0; i < 8; i++) {
                float a = xs[ty * 8 + i][kk];
#pragma unroll
                for (int j = 0; j < 4; j++) acc[i][j] += a * b[j];
            }
        }
        __syncthreads();
    }
    for (int i = 0; i < 8; i++) {
        int n = n0 + ty * 8 + i;
        if (n < N) {
#pragma unroll
            for (int j = 0; j < 4; j++)
                Wh2[(size_t)n * HID + tx * 4 + j] = acc[i][j];
        }
    }
}

// K5: g1/g2
__global__ void calc_g(const float* __restrict__ Wh2,
                       const float* __restrict__ a_out,
                       float* __restrict__ g1, float* __restrict__ g2) {
    int t = threadIdx.x, lane = t & 63, w = t >> 6;
    int n = blockIdx.x * 4 + w;
    const float* r = Wh2 + (size_t)n * HID;
    float v0 = r[lane], v1 = r[64 + lane];
    float s1 = v0 * a_out[lane] + v1 * a_out[64 + lane];
    float s2 = v0 * a_out[128 + lane] + v1 * a_out[192 + lane];
    for (int d = 32; d; d >>= 1) { s1 += __shfl_xor(s1, d); s2 += __shfl_xor(s2, d); }
    if (lane == 0) { g1[n] = s1; g2[n] = s2; }
}

// K6: layer-2 fused masked-softmax + PV (sparse), same structure as gat1
__global__ void gat2(const float* __restrict__ Wh2,
                     const float* __restrict__ g1, const float* __restrict__ g2,
                     const unsigned short* __restrict__ nbr,
                     const int* __restrict__ ncnt,
                     float* __restrict__ out) {
    int n = blockIdx.x, t = threadIdx.x;
    int s = t >> 5, op = t & 31;
    int cnt = ncnt[n];
    const unsigned short* lst = nbr + (size_t)n * NBR_CAP;
    __shared__ float wl[NBR_CAP];
    __shared__ int   ml[NBR_CAP];
    __shared__ float4 accl[8][32];
    __shared__ float swl[8];

    float g1c = g1[n];
    for (int i = t; i < cnt; i += 256) {
        int m = lst[i];
        ml[i] = m;
        float z = g1c + g2[m];
        z = (z >= 0.f) ? z : ALPHA * z;
        wl[i] = __expf(z);
    }
    __syncthreads();

    float4 acc = {0.f, 0.f, 0.f, 0.f};
    float sw = 0.f;
    for (int j = s; j < cnt; j += 8) {
        float wj = wl[j];
        const float4 v = *(const float4*)(Wh2 + (size_t)ml[j] * HID + 4 * op);
        acc.x += wj * v.x; acc.y += wj * v.y;
        acc.z += wj * v.z; acc.w += wj * v.w;
        sw += wj;
    }
    accl[s][op] = acc;
    if (op == 0) swl[s] = sw;
    __syncthreads();

    if (t < 32) {
        float4 r = accl[0][t];
#pragma unroll
        for (int k = 1; k < 8; k++) {
            float4 q = accl[k][t];
            r.x += q.x; r.y += q.y; r.z += q.z; r.w += q.w;
        }
        float swt = 0.f;
#pragma unroll
        for (int k = 0; k < 8; k++) swt += swl[k];
        float inv = 1.f / swt;
        *(float4*)(out + (size_t)n * HID + 4 * t) =
            make_float4(r.x * inv, r.y * inv, r.z * inv, r.w * inv);
    }
}

extern "C" void kernel_launch(void* const* d_in, const int* in_sizes, int n_in,
                              void* d_out, int out_size, void* d_ws, size_t ws_size,
                              hipStream_t stream) {
    const float* x       = (const float*)d_in[0];
    const float* adj     = (const float*)d_in[1];
    const float* W_heads = (const float*)d_in[2];
    const float* a_heads = (const float*)d_in[3];
    const float* W_out   = (const float*)d_in[4];
    const float* a_out   = (const float*)d_in[5];
    float* out = (float*)d_out;

    char* wsb = (char*)d_ws;
    size_t off = 0;
    auto alloc = [&](size_t bytes) {
        void* p = wsb + off;
        off += (bytes + 255) & ~(size_t)255;
        return p;
    };
    float* Wh   = (float*)alloc(sizeof(float) * (size_t)NH * N * HID);
    float* hcat = (float*)alloc(sizeof(float) * (size_t)N * NH * HID);
    float* Wh2  = (float*)alloc(sizeof(float) * (size_t)N * HID);
    float* f1   = (float*)alloc(sizeof(float) * (size_t)NH * N);
    float* f2   = (float*)alloc(sizeof(float) * (size_t)NH * N);
    float* g1   = (float*)alloc(sizeof(float) * (size_t)N);
    float* g2   = (float*)alloc(sizeof(float) * (size_t)N);
    unsigned short* nbr = (unsigned short*)alloc(sizeof(unsigned short) * (size_t)N * NBR_CAP);
    int* ncnt = (int*)alloc(sizeof(int) * (size_t)N);

    hipLaunchKernelGGL(build_nbr, dim3(N), dim3(256), 0, stream, adj, nbr, ncnt);
    hipLaunchKernelGGL(gemm_wh, dim3((N + 63) / 64, NH), dim3(256), 0, stream, x, W_heads, Wh);
    hipLaunchKernelGGL(calc_f, dim3(NH * N / 4), dim3(256), 0, stream, Wh, a_heads, f1, f2);
    hipLaunchKernelGGL(gat1, dim3(NH * N), dim3(256), 0, stream, Wh, f1, f2, nbr, ncnt, hcat);
    hipLaunchKernelGGL(gemm_out, dim3((N + 63) / 64), dim3(256), 0, stream, hcat, W_out, Wh2);
    hipLaunchKernelGGL(calc_g, dim3(N / 4), dim3(256), 0, stream, Wh2, a_out, g1, g2);
    hipLaunchKernelGGL(gat2, dim3(N), dim3(256), 0, stream, Wh2, g1, g2, nbr, ncnt, out);
}

// Round 3
// 527.468 us; speedup vs baseline: 2.1215x; 1.2730x over previous
//
#include <hip/hip_runtime.h>
#include <math.h>

#define N 6000
#define FIN 300
#define HID 128
#define NH 8
#define ALPHA 0.2f
#define NBR_CAP 512

typedef unsigned short u16;
typedef unsigned int u32;

static __device__ __forceinline__ u16 f2bf(float f) {
    u32 u = __float_as_uint(f);
    u32 r = (u + 0x7fff + ((u >> 16) & 1)) >> 16;   // round-to-nearest-even
    return (u16)r;
}

// K0: build neighbor lists; per-wave private segment, 1 barrier, float4 loads
__global__ void build_nbr(const float* __restrict__ adj,
                          u16* __restrict__ nbr,
                          int* __restrict__ ncnt) {
    int n = blockIdx.x;
    int t = threadIdx.x;
    int lane = t & 63, w = t >> 6;
    __shared__ u16 lbuf[4][256];
    __shared__ int wc[4];
    const int seg = N / 4;                 // 1500
    int start = w * seg, end = start + seg;
    const float* row = adj + (size_t)n * N;
    int cnt = 0;
    for (int base = start; base < end; base += 256) {
        int m0 = base + 4 * lane;
        float4 v = make_float4(0.f, 0.f, 0.f, 0.f);
        if (m0 < end) v = *(const float4*)(row + m0);
#pragma unroll
        for (int c = 0; c < 4; c++) {
            float vc = (c == 0) ? v.x : (c == 1) ? v.y : (c == 2) ? v.z : v.w;
            bool p = vc > 0.5f;
            unsigned long long mask = __ballot(p);
            if (p) {
                int pos = cnt + __popcll(mask & ((1ull << lane) - 1ull));
                if (pos < 256) lbuf[w][pos] = (u16)(m0 + c);
            }
            cnt += __popcll(mask);
        }
    }
    if (cnt > 256) cnt = 256;
    if (lane == 0) wc[w] = cnt;
    __syncthreads();
    int offset = 0;
    for (int i = 0; i < w; i++) offset += wc[i];
    for (int i = lane; i < cnt; i += 64) {
        int idx = offset + i;
        if (idx < NBR_CAP) nbr[(size_t)n * NBR_CAP + idx] = lbuf[w][i];
    }
    if (t == 0) {
        int total = wc[0] + wc[1] + wc[2] + wc[3];
        ncnt[n] = total < NBR_CAP ? total : NBR_CAP;
    }
}

// K1: Wh = x @ W_heads (fp32), plus bf16 shadow Whb for the PV gather
__global__ void gemm_wh(const float* __restrict__ x,
                        const float* __restrict__ W,
                        float* __restrict__ Wh,
                        u16* __restrict__ Whb) {
    int h = blockIdx.y;
    int n0 = blockIdx.x * 64;
    __shared__ float xs[64][13];
    __shared__ float bs[12][128];
    int t = threadIdx.x;
    int tx = t & 31, ty = t >> 5;
    float acc[8][4] = {};
    for (int k0 = 0; k0 < FIN; k0 += 12) {
        for (int i = t; i < 64 * 12; i += 256) {
            int r = i / 12, c = i - r * 12;
            int n = n0 + r;
            xs[r][c] = (n < N) ? x[(size_t)n * FIN + k0 + c] : 0.f;
        }
        for (int i = t; i < 12 * 128; i += 256) {
            int r = i >> 7, c = i & 127;
            bs[r][c] = W[((size_t)h * FIN + (k0 + r)) * HID + c];
        }
        __syncthreads();
#pragma unroll
        for (int kk = 0; kk < 12; kk++) {
            float b[4];
#pragma unroll
            for (int j = 0; j < 4; j++) b[j] = bs[kk][tx * 4 + j];
#pragma unroll
            for (int i = 0; i < 8; i++) {
                float a = xs[ty * 8 + i][kk];
#pragma unroll
                for (int j = 0; j < 4; j++) acc[i][j] += a * b[j];
            }
        }
        __syncthreads();
    }
    for (int i = 0; i < 8; i++) {
        int n = n0 + ty * 8 + i;
        if (n < N) {
            size_t ro = ((size_t)h * N + n) * HID + tx * 4;
            float* o = Wh + ro;
#pragma unroll
            for (int j = 0; j < 4; j++) o[j] = acc[i][j];
            ushort4 b4;
            b4.x = f2bf(acc[i][0]); b4.y = f2bf(acc[i][1]);
            b4.z = f2bf(acc[i][2]); b4.w = f2bf(acc[i][3]);
            *(ushort4*)(Whb + ro) = b4;
        }
    }
}

// K2: f1/f2 per (h,n); one wave per pair (fp32 Wh)
__global__ void calc_f(const float* __restrict__ Wh,
                       const float* __restrict__ a_heads,
                       float* __restrict__ f1, float* __restrict__ f2) {
    int t = threadIdx.x, lane = t & 63, w = t >> 6;
    int pid = blockIdx.x * 4 + w;
    int h = pid / N, n = pid - h * N;
    const float* r = Wh + ((size_t)h * N + n) * HID;
    const float* a = a_heads + (size_t)h * 2 * HID;
    float v0 = r[lane], v1 = r[64 + lane];
    float s1 = v0 * a[lane] + v1 * a[64 + lane];
    float s2 = v0 * a[128 + lane] + v1 * a[192 + lane];
    for (int d = 32; d; d >>= 1) { s1 += __shfl_xor(s1, d); s2 += __shfl_xor(s2, d); }
    if (lane == 0) { f1[h * N + n] = s1; f2[h * N + n] = s2; }
}

// K3: layer-1 fused masked-softmax + PV, per-head blocks (head-major),
// bf16 gather: 16 neighbor-streams x 16 lanes x 8 cols, 16 B/lane uint4.
__global__ void gat1(const u16* __restrict__ Whb,
                     const float* __restrict__ f1, const float* __restrict__ f2,
                     const u16* __restrict__ nbr,
                     const int* __restrict__ ncnt,
                     float* __restrict__ hcat) {
    int bid = blockIdx.x;
    int h = bid / N, n = bid - h * N;
    int t = threadIdx.x;
    int s = t >> 4, op = t & 15;
    int cnt = ncnt[n];
    const u16* lst = nbr + (size_t)n * NBR_CAP;
    __shared__ float wl[NBR_CAP];
    __shared__ u16   ml[NBR_CAP];
    __shared__ float accl[16][16][8];
    __shared__ float swl[16];

    float f1c = f1[h * N + n];
    for (int i = t; i < cnt; i += 256) {
        int m = lst[i];
        ml[i] = (u16)m;
        float z = f1c + f2[h * N + m];
        z = (z >= 0.f) ? z : ALPHA * z;
        wl[i] = __expf(z);
    }
    __syncthreads();

    const u16* base = Whb + (size_t)h * N * HID;
    float acc[8] = {};
    float sw = 0.f;
    for (int j = s; j < cnt; j += 16) {
        float wj = wl[j];
        int m = ml[j];
        const uint4 v = *(const uint4*)(base + (size_t)m * HID + (op << 3));
        float c0 = __uint_as_float(v.x << 16);
        float c1 = __uint_as_float(v.x & 0xffff0000u);
        float c2 = __uint_as_float(v.y << 16);
        float c3 = __uint_as_float(v.y & 0xffff0000u);
        float c4 = __uint_as_float(v.z << 16);
        float c5 = __uint_as_float(v.z & 0xffff0000u);
        float c6 = __uint_as_float(v.w << 16);
        float c7 = __uint_as_float(v.w & 0xffff0000u);
        acc[0] += wj * c0; acc[1] += wj * c1;
        acc[2] += wj * c2; acc[3] += wj * c3;
        acc[4] += wj * c4; acc[5] += wj * c5;
        acc[6] += wj * c6; acc[7] += wj * c7;
        sw += wj;
    }
    *(float4*)&accl[s][op][0] = make_float4(acc[0], acc[1], acc[2], acc[3]);
    *(float4*)&accl[s][op][4] = make_float4(acc[4], acc[5], acc[6], acc[7]);
    if (op == 0) swl[s] = sw;
    __syncthreads();

    if (t < 128) {
        int c = t;
        float r = 0.f;
#pragma unroll
        for (int k = 0; k < 16; k++) r += accl[k][c >> 3][c & 7];
        float swt = 0.f;
#pragma unroll
        for (int k = 0; k < 16; k++) swt += swl[k];
        r /= swt;
        r = (r > 0.f) ? r : expm1f(r);
        hcat[(size_t)n * (NH * HID) + h * HID + c] = r;
    }
}

// K4: Wh2 = hcat(6000x1024) @ W_out(1024x128)
__global__ void gemm_out(const float* __restrict__ hcat,
                         const float* __restrict__ W_out,
                         float* __restrict__ Wh2) {
    int n0 = blockIdx.x * 64;
    __shared__ float xs[64][17];
    __shared__ float bs[16][128];
    int t = threadIdx.x;
    int tx = t & 31, ty = t >> 5;
    float acc[8][4] = {};
    for (int k0 = 0; k0 < 1024; k0 += 16) {
        for (int i = t; i < 64 * 16; i += 256) {
            int r = i >> 4, c = i & 15;
            int n = n0 + r;
            xs[r][c] = (n < N) ? hcat[(size_t)n * 1024 + k0 + c] : 0.f;
        }
        for (int i = t; i < 16 * 128; i += 256) {
            int r = i >> 7, c = i & 127;
            bs[r][c] = W_out[(size_t)(k0 + r) * HID + c];
        }
        __syncthreads();
#pragma unroll
        for (int kk = 0; kk < 16; kk++) {
            float b[4];
#pragma unroll
            for (int j = 0; j < 4; j++) b[j] = bs[kk][tx * 4 + j];
#pragma unroll
            for (int i = 0; i < 8; i++) {
                float a = xs[ty * 8 + i][kk];
#pragma unroll
                for (int j = 0; j < 4; j++) acc[i][j] += a * b[j];
            }
        }
        __syncthreads();
    }
    for (int i = 0; i < 8; i++) {
        int n = n0 + ty * 8 + i;
        if (n < N) {
#pragma unroll
            for (int j = 0; j < 4; j++)
                Wh2[(size_t)n * HID + tx * 4 + j] = acc[i][j];
        }
    }
}

// K5: g1/g2
__global__ void calc_g(const float* __restrict__ Wh2,
                       const float* __restrict__ a_out,
                       float* __restrict__ g1, float* __restrict__ g2) {
    int t = threadIdx.x, lane = t & 63, w = t >> 6;
    int n = blockIdx.x * 4 + w;
    const float* r = Wh2 + (size_t)n * HID;
    float v0 = r[lane], v1 = r[64 + lane];
    float s1 = v0 * a_out[lane] + v1 * a_out[64 + lane];
    float s2 = v0 * a_out[128 + lane] + v1 * a_out[192 + lane];
    for (int d = 32; d; d >>= 1) { s1 += __shfl_xor(s1, d); s2 += __shfl_xor(s2, d); }
    if (lane == 0) { g1[n] = s1; g2[n] = s2; }
}

// K6: layer-2 fused masked-softmax + PV (fp32, feeds output directly)
__global__ void gat2(const float* __restrict__ Wh2,
                     const float* __restrict__ g1, const float* __restrict__ g2,
                     const u16* __restrict__ nbr,
                     const int* __restrict__ ncnt,
                     float* __restrict__ out) {
    int n = blockIdx.x, t = threadIdx.x;
    int s = t >> 5, op = t & 31;
    int cnt = ncnt[n];
    const u16* lst = nbr + (size_t)n * NBR_CAP;
    __shared__ float wl[NBR_CAP];
    __shared__ int   ml[NBR_CAP];
    __shared__ float4 accl[8][32];
    __shared__ float swl[8];

    float g1c = g1[n];
    for (int i = t; i < cnt; i += 256) {
        int m = lst[i];
        ml[i] = m;
        float z = g1c + g2[m];
        z = (z >= 0.f) ? z : ALPHA * z;
        wl[i] = __expf(z);
    }
    __syncthreads();

    float4 acc = {0.f, 0.f, 0.f, 0.f};
    float sw = 0.f;
    for (int j = s; j < cnt; j += 8) {
        float wj = wl[j];
        const float4 v = *(const float4*)(Wh2 + (size_t)ml[j] * HID + 4 * op);
        acc.x += wj * v.x; acc.y += wj * v.y;
        acc.z += wj * v.z; acc.w += wj * v.w;
        sw += wj;
    }
    accl[s][op] = acc;
    if (op == 0) swl[s] = sw;
    __syncthreads();

    if (t < 32) {
        float4 r = accl[0][t];
#pragma unroll
        for (int k = 1; k < 8; k++) {
            float4 q = accl[k][t];
            r.x += q.x; r.y += q.y; r.z += q.z; r.w += q.w;
        }
        float swt = 0.f;
#pragma unroll
        for (int k = 0; k < 8; k++) swt += swl[k];
        float inv = 1.f / swt;
        *(float4*)(out + (size_t)n * HID + 4 * t) =
            make_float4(r.x * inv, r.y * inv, r.z * inv, r.w * inv);
    }
}

extern "C" void kernel_launch(void* const* d_in, const int* in_sizes, int n_in,
                              void* d_out, int out_size, void* d_ws, size_t ws_size,
                              hipStream_t stream) {
    const float* x       = (const float*)d_in[0];
    const float* adj     = (const float*)d_in[1];
    const float* W_heads = (const float*)d_in[2];
    const float* a_heads = (const float*)d_in[3];
    const float* W_out   = (const float*)d_in[4];
    const float* a_out   = (const float*)d_in[5];
    float* out = (float*)d_out;

    char* wsb = (char*)d_ws;
    size_t off = 0;
    auto alloc = [&](size_t bytes) {
        void* p = wsb + off;
        off += (bytes + 255) & ~(size_t)255;
        return p;
    };
    float* Wh   = (float*)alloc(sizeof(float) * (size_t)NH * N * HID);
    u16*   Whb  = (u16*)  alloc(sizeof(u16)   * (size_t)NH * N * HID);
    float* hcat = (float*)alloc(sizeof(float) * (size_t)N * NH * HID);
    float* Wh2  = (float*)alloc(sizeof(float) * (size_t)N * HID);
    float* f1   = (float*)alloc(sizeof(float) * (size_t)NH * N);
    float* f2   = (float*)alloc(sizeof(float) * (size_t)NH * N);
    float* g1   = (float*)alloc(sizeof(float) * (size_t)N);
    float* g2   = (float*)alloc(sizeof(float) * (size_t)N);
    u16* nbr    = (u16*)  alloc(sizeof(u16)   * (size_t)N * NBR_CAP);
    int* ncnt   = (int*)  alloc(sizeof(int)   * (size_t)N);

    hipLaunchKernelGGL(build_nbr, dim3(N), dim3(256), 0, stream, adj, nbr, ncnt);
    hipLaunchKernelGGL(gemm_wh, dim3((N + 63) / 64, NH), dim3(256), 0, stream, x, W_heads, Wh, Whb);
    hipLaunchKernelGGL(calc_f, dim3(NH * N / 4), dim3(256), 0, stream, Wh, a_heads, f1, f2);
    hipLaunchKernelGGL(gat1, dim3(NH * N), dim3(256), 0, stream, Whb, f1, f2, nbr, ncnt, hcat);
    hipLaunchKernelGGL(gemm_out, dim3((N + 63) / 64), dim3(256), 0, stream, hcat, W_out, Wh2);
    hipLaunchKernelGGL(calc_g, dim3(N / 4), dim3(256), 0, stream, Wh2, a_out, g1, g2);
    hipLaunchKernelGGL(gat2, dim3(N), dim3(256), 0, stream, Wh2, g1, g2, nbr, ncnt, out);
}

// Round 4
// 383.488 us; speedup vs baseline: 2.9180x; 1.3754x over previous
//
#include <hip/hip_runtime.h>
#include <math.h>

#define N 6000
#define FIN 300
#define HID 128
#define NH 8
#define ALPHA 0.2f
#define NBR_CAP 512
#define KSPLIT 8

typedef unsigned short u16;
typedef unsigned int u32;

static __device__ __forceinline__ u16 f2bf(float f) {
    u32 u = __float_as_uint(f);
    u32 r = (u + 0x7fff + ((u >> 16) & 1)) >> 16;   // round-to-nearest-even
    return (u16)r;
}

// K0: build neighbor lists; per-wave private segment, 1 barrier, float4 loads
__global__ void build_nbr(const float* __restrict__ adj,
                          u16* __restrict__ nbr,
                          int* __restrict__ ncnt) {
    int n = blockIdx.x;
    int t = threadIdx.x;
    int lane = t & 63, w = t >> 6;
    __shared__ u16 lbuf[4][256];
    __shared__ int wc[4];
    const int seg = N / 4;                 // 1500
    int start = w * seg, end = start + seg;
    const float* row = adj + (size_t)n * N;
    int cnt = 0;
    for (int base = start; base < end; base += 256) {
        int m0 = base + 4 * lane;
        float4 v = make_float4(0.f, 0.f, 0.f, 0.f);
        if (m0 < end) v = *(const float4*)(row + m0);
#pragma unroll
        for (int c = 0; c < 4; c++) {
            float vc = (c == 0) ? v.x : (c == 1) ? v.y : (c == 2) ? v.z : v.w;
            bool p = vc > 0.5f;
            unsigned long long mask = __ballot(p);
            if (p) {
                int pos = cnt + __popcll(mask & ((1ull << lane) - 1ull));
                if (pos < 256) lbuf[w][pos] = (u16)(m0 + c);
            }
            cnt += __popcll(mask);
        }
    }
    if (cnt > 256) cnt = 256;
    if (lane == 0) wc[w] = cnt;
    __syncthreads();
    int offset = 0;
    for (int i = 0; i < w; i++) offset += wc[i];
    for (int i = lane; i < cnt; i += 64) {
        int idx = offset + i;
        if (idx < NBR_CAP) nbr[(size_t)n * NBR_CAP + idx] = lbuf[w][i];
    }
    if (t == 0) {
        int total = wc[0] + wc[1] + wc[2] + wc[3];
        ncnt[n] = total < NBR_CAP ? total : NBR_CAP;
    }
}

// K1: Wh = x @ W_heads (fp32), plus bf16 shadow Whb for the PV gather
__global__ void gemm_wh(const float* __restrict__ x,
                        const float* __restrict__ W,
                        float* __restrict__ Wh,
                        u16* __restrict__ Whb) {
    int h = blockIdx.y;
    int n0 = blockIdx.x * 64;
    __shared__ float xs[64][13];
    __shared__ float bs[12][128];
    int t = threadIdx.x;
    int tx = t & 31, ty = t >> 5;
    float acc[8][4] = {};
    for (int k0 = 0; k0 < FIN; k0 += 12) {
        for (int i = t; i < 64 * 12; i += 256) {
            int r = i / 12, c = i - r * 12;
            int n = n0 + r;
            xs[r][c] = (n < N) ? x[(size_t)n * FIN + k0 + c] : 0.f;
        }
        for (int i = t; i < 12 * 128; i += 256) {
            int r = i >> 7, c = i & 127;
            bs[r][c] = W[((size_t)h * FIN + (k0 + r)) * HID + c];
        }
        __syncthreads();
#pragma unroll
        for (int kk = 0; kk < 12; kk++) {
            float b[4];
#pragma unroll
            for (int j = 0; j < 4; j++) b[j] = bs[kk][tx * 4 + j];
#pragma unroll
            for (int i = 0; i < 8; i++) {
                float a = xs[ty * 8 + i][kk];
#pragma unroll
                for (int j = 0; j < 4; j++) acc[i][j] += a * b[j];
            }
        }
        __syncthreads();
    }
    for (int i = 0; i < 8; i++) {
        int n = n0 + ty * 8 + i;
        if (n < N) {
            size_t ro = ((size_t)h * N + n) * HID + tx * 4;
            float* o = Wh + ro;
#pragma unroll
            for (int j = 0; j < 4; j++) o[j] = acc[i][j];
            ushort4 b4;
            b4.x = f2bf(acc[i][0]); b4.y = f2bf(acc[i][1]);
            b4.z = f2bf(acc[i][2]); b4.w = f2bf(acc[i][3]);
            *(ushort4*)(Whb + ro) = b4;
        }
    }
}

// K2: f1/f2 per (h,n); one wave per pair (fp32 Wh)
__global__ void calc_f(const float* __restrict__ Wh,
                       const float* __restrict__ a_heads,
                       float* __restrict__ f1, float* __restrict__ f2) {
    int t = threadIdx.x, lane = t & 63, w = t >> 6;
    int pid = blockIdx.x * 4 + w;
    int h = pid / N, n = pid - h * N;
    const float* r = Wh + ((size_t)h * N + n) * HID;
    const float* a = a_heads + (size_t)h * 2 * HID;
    float v0 = r[lane], v1 = r[64 + lane];
    float s1 = v0 * a[lane] + v1 * a[64 + lane];
    float s2 = v0 * a[128 + lane] + v1 * a[192 + lane];
    for (int d = 32; d; d >>= 1) { s1 += __shfl_xor(s1, d); s2 += __shfl_xor(s2, d); }
    if (lane == 0) { f1[h * N + n] = s1; f2[h * N + n] = s2; }
}

// K3: layer-1 fused masked-softmax + PV, per-head blocks (head-major),
// bf16 gather: 16 neighbor-streams x 16 lanes x 8 cols, 16 B/lane uint4.
__global__ void gat1(const u16* __restrict__ Whb,
                     const float* __restrict__ f1, const float* __restrict__ f2,
                     const u16* __restrict__ nbr,
                     const int* __restrict__ ncnt,
                     float* __restrict__ hcat) {
    int bid = blockIdx.x;
    int h = bid / N, n = bid - h * N;
    int t = threadIdx.x;
    int s = t >> 4, op = t & 15;
    int cnt = ncnt[n];
    const u16* lst = nbr + (size_t)n * NBR_CAP;
    __shared__ float wl[NBR_CAP];
    __shared__ u16   ml[NBR_CAP];
    __shared__ float accl[16][16][8];
    __shared__ float swl[16];

    float f1c = f1[h * N + n];
    for (int i = t; i < cnt; i += 256) {
        int m = lst[i];
        ml[i] = (u16)m;
        float z = f1c + f2[h * N + m];
        z = (z >= 0.f) ? z : ALPHA * z;
        wl[i] = __expf(z);
    }
    __syncthreads();

    const u16* base = Whb + (size_t)h * N * HID;
    float acc[8] = {};
    float sw = 0.f;
    for (int j = s; j < cnt; j += 16) {
        float wj = wl[j];
        int m = ml[j];
        const uint4 v = *(const uint4*)(base + (size_t)m * HID + (op << 3));
        float c0 = __uint_as_float(v.x << 16);
        float c1 = __uint_as_float(v.x & 0xffff0000u);
        float c2 = __uint_as_float(v.y << 16);
        float c3 = __uint_as_float(v.y & 0xffff0000u);
        float c4 = __uint_as_float(v.z << 16);
        float c5 = __uint_as_float(v.z & 0xffff0000u);
        float c6 = __uint_as_float(v.w << 16);
        float c7 = __uint_as_float(v.w & 0xffff0000u);
        acc[0] += wj * c0; acc[1] += wj * c1;
        acc[2] += wj * c2; acc[3] += wj * c3;
        acc[4] += wj * c4; acc[5] += wj * c5;
        acc[6] += wj * c6; acc[7] += wj * c7;
        sw += wj;
    }
    *(float4*)&accl[s][op][0] = make_float4(acc[0], acc[1], acc[2], acc[3]);
    *(float4*)&accl[s][op][4] = make_float4(acc[4], acc[5], acc[6], acc[7]);
    if (op == 0) swl[s] = sw;
    __syncthreads();

    if (t < 128) {
        int c = t;
        float r = 0.f;
#pragma unroll
        for (int k = 0; k < 16; k++) r += accl[k][c >> 3][c & 7];
        float swt = 0.f;
#pragma unroll
        for (int k = 0; k < 16; k++) swt += swl[k];
        r /= swt;
        r = (r > 0.f) ? r : expm1f(r);
        hcat[(size_t)n * (NH * HID) + h * HID + c] = r;
    }
}

// K4: Wh2 = hcat(6000x1024) @ W_out(1024x128), split-K over 8 slices of 128.
// grid (94, 8); block (i,s) writes partial[s][n0:n0+64][0:128] exclusively.
__global__ void gemm_out(const float* __restrict__ hcat,
                         const float* __restrict__ W_out,
                         float* __restrict__ partial) {
    int n0 = blockIdx.x * 64;
    int ks = blockIdx.y;
    __shared__ float xs[64][17];
    __shared__ float bs[16][128];
    int t = threadIdx.x;
    int tx = t & 31, ty = t >> 5;
    float acc[8][4] = {};
    int kbeg = ks * 128, kend = kbeg + 128;
    for (int k0 = kbeg; k0 < kend; k0 += 16) {
        for (int i = t; i < 64 * 16; i += 256) {
            int r = i >> 4, c = i & 15;
            int n = n0 + r;
            xs[r][c] = (n < N) ? hcat[(size_t)n * 1024 + k0 + c] : 0.f;
        }
        for (int i = t; i < 16 * 128; i += 256) {
            int r = i >> 7, c = i & 127;
            bs[r][c] = W_out[(size_t)(k0 + r) * HID + c];
        }
        __syncthreads();
#pragma unroll
        for (int kk = 0; kk < 16; kk++) {
            float b[4];
#pragma unroll
            for (int j = 0; j < 4; j++) b[j] = bs[kk][tx * 4 + j];
#pragma unroll
            for (int i = 0; i < 8; i++) {
                float a = xs[ty * 8 + i][kk];
#pragma unroll
                for (int j = 0; j < 4; j++) acc[i][j] += a * b[j];
            }
        }
        __syncthreads();
    }
    float* pout = partial + (size_t)ks * N * HID;
    for (int i = 0; i < 8; i++) {
        int n = n0 + ty * 8 + i;
        if (n < N) {
#pragma unroll
            for (int j = 0; j < 4; j++)
                pout[(size_t)n * HID + tx * 4 + j] = acc[i][j];
        }
    }
}

// K4b: Wh2 = sum over the 8 K-split partials (float4 vectorized)
__global__ void reduce_wh2(const float* __restrict__ partial,
                           float* __restrict__ Wh2) {
    int idx = blockIdx.x * 256 + threadIdx.x;      // float4 index
    const int tot4 = N * HID / 4;                  // 192000
    if (idx >= tot4) return;
    float4 v = *(const float4*)(partial + 4 * (size_t)idx);
#pragma unroll
    for (int s = 1; s < KSPLIT; s++) {
        const float4 q = *(const float4*)(partial + (size_t)s * N * HID + 4 * (size_t)idx);
        v.x += q.x; v.y += q.y; v.z += q.z; v.w += q.w;
    }
    *(float4*)(Wh2 + 4 * (size_t)idx) = v;
}

// K5: g1/g2
__global__ void calc_g(const float* __restrict__ Wh2,
                       const float* __restrict__ a_out,
                       float* __restrict__ g1, float* __restrict__ g2) {
    int t = threadIdx.x, lane = t & 63, w = t >> 6;
    int n = blockIdx.x * 4 + w;
    const float* r = Wh2 + (size_t)n * HID;
    float v0 = r[lane], v1 = r[64 + lane];
    float s1 = v0 * a_out[lane] + v1 * a_out[64 + lane];
    float s2 = v0 * a_out[128 + lane] + v1 * a_out[192 + lane];
    for (int d = 32; d; d >>= 1) { s1 += __shfl_xor(s1, d); s2 += __shfl_xor(s2, d); }
    if (lane == 0) { g1[n] = s1; g2[n] = s2; }
}

// K6: layer-2 fused masked-softmax + PV (fp32, feeds output directly)
__global__ void gat2(const float* __restrict__ Wh2,
                     const float* __restrict__ g1, const float* __restrict__ g2,
                     const u16* __restrict__ nbr,
                     const int* __restrict__ ncnt,
                     float* __restrict__ out) {
    int n = blockIdx.x, t = threadIdx.x;
    int s = t >> 5, op = t & 31;
    int cnt = ncnt[n];
    const u16* lst = nbr + (size_t)n * NBR_CAP;
    __shared__ float wl[NBR_CAP];
    __shared__ int   ml[NBR_CAP];
    __shared__ float4 accl[8][32];
    __shared__ float swl[8];

    float g1c = g1[n];
    for (int i = t; i < cnt; i += 256) {
        int m = lst[i];
        ml[i] = m;
        float z = g1c + g2[m];
        z = (z >= 0.f) ? z : ALPHA * z;
        wl[i] = __expf(z);
    }
    __syncthreads();

    float4 acc = {0.f, 0.f, 0.f, 0.f};
    float sw = 0.f;
    for (int j = s; j < cnt; j += 8) {
        float wj = wl[j];
        const float4 v = *(const float4*)(Wh2 + (size_t)ml[j] * HID + 4 * op);
        acc.x += wj * v.x; acc.y += wj * v.y;
        acc.z += wj * v.z; acc.w += wj * v.w;
        sw += wj;
    }
    accl[s][op] = acc;
    if (op == 0) swl[s] = sw;
    __syncthreads();

    if (t < 32) {
        float4 r = accl[0][t];
#pragma unroll
        for (int k = 1; k < 8; k++) {
            float4 q = accl[k][t];
            r.x += q.x; r.y += q.y; r.z += q.z; r.w += q.w;
        }
        float swt = 0.f;
#pragma unroll
        for (int k = 0; k < 8; k++) swt += swl[k];
        float inv = 1.f / swt;
        *(float4*)(out + (size_t)n * HID + 4 * t) =
            make_float4(r.x * inv, r.y * inv, r.z * inv, r.w * inv);
    }
}

extern "C" void kernel_launch(void* const* d_in, const int* in_sizes, int n_in,
                              void* d_out, int out_size, void* d_ws, size_t ws_size,
                              hipStream_t stream) {
    const float* x       = (const float*)d_in[0];
    const float* adj     = (const float*)d_in[1];
    const float* W_heads = (const float*)d_in[2];
    const float* a_heads = (const float*)d_in[3];
    const float* W_out   = (const float*)d_in[4];
    const float* a_out   = (const float*)d_in[5];
    float* out = (float*)d_out;

    char* wsb = (char*)d_ws;
    size_t off = 0;
    auto alloc = [&](size_t bytes) {
        void* p = wsb + off;
        off += (bytes + 255) & ~(size_t)255;
        return p;
    };
    float* Wh   = (float*)alloc(sizeof(float) * (size_t)NH * N * HID);  // 24.576 MB
    u16*   Whb  = (u16*)  alloc(sizeof(u16)   * (size_t)NH * N * HID);
    float* hcat = (float*)alloc(sizeof(float) * (size_t)N * NH * HID);
    float* Wh2  = (float*)alloc(sizeof(float) * (size_t)N * HID);
    float* f1   = (float*)alloc(sizeof(float) * (size_t)NH * N);
    float* f2   = (float*)alloc(sizeof(float) * (size_t)NH * N);
    float* g1   = (float*)alloc(sizeof(float) * (size_t)N);
    float* g2   = (float*)alloc(sizeof(float) * (size_t)N);
    u16* nbr    = (u16*)  alloc(sizeof(u16)   * (size_t)N * NBR_CAP);
    int* ncnt   = (int*)  alloc(sizeof(int)   * (size_t)N);

    // partial[KSPLIT][N][HID] aliases Wh: KSPLIT*N*HID == NH*N*HID floats,
    // and Wh's last reader (calc_f) runs before gemm_out in stream order.
    float* partial = Wh;

    hipLaunchKernelGGL(build_nbr, dim3(N), dim3(256), 0, stream, adj, nbr, ncnt);
    hipLaunchKernelGGL(gemm_wh, dim3((N + 63) / 64, NH), dim3(256), 0, stream, x, W_heads, Wh, Whb);
    hipLaunchKernelGGL(calc_f, dim3(NH * N / 4), dim3(256), 0, stream, Wh, a_heads, f1, f2);
    hipLaunchKernelGGL(gat1, dim3(NH * N), dim3(256), 0, stream, Whb, f1, f2, nbr, ncnt, hcat);
    hipLaunchKernelGGL(gemm_out, dim3((N + 63) / 64, KSPLIT), dim3(256), 0, stream, hcat, W_out, partial);
    hipLaunchKernelGGL(reduce_wh2, dim3((N * HID / 4 + 255) / 256), dim3(256), 0, stream, partial, Wh2);
    hipLaunchKernelGGL(calc_g, dim3(N / 4), dim3(256), 0, stream, Wh2, a_out, g1, g2);
    hipLaunchKernelGGL(gat2, dim3(N), dim3(256), 0, stream, Wh2, g1, g2, nbr, ncnt, out);
}

// Round 5
// 366.851 us; speedup vs baseline: 3.0503x; 1.0453x over previous
//
#include <hip/hip_runtime.h>
#include <math.h>

#define N 6000
#define FIN 300
#define HID 128
#define NH 8
#define ALPHA 0.2f
#define NBR_CAP 512
#define KSPLIT 8

typedef unsigned short u16;
typedef unsigned int u32;

static __device__ __forceinline__ u16 f2bf(float f) {
    u32 u = __float_as_uint(f);
    u32 r = (u + 0x7fff + ((u >> 16) & 1)) >> 16;   // round-to-nearest-even
    return (u16)r;
}

// K0: build neighbor lists; per-wave private segment, 1 barrier, float4 loads
__global__ void build_nbr(const float* __restrict__ adj,
                          u16* __restrict__ nbr,
                          int* __restrict__ ncnt) {
    int n = blockIdx.x;
    int t = threadIdx.x;
    int lane = t & 63, w = t >> 6;
    __shared__ u16 lbuf[4][256];
    __shared__ int wc[4];
    const int seg = N / 4;                 // 1500
    int start = w * seg, end = start + seg;
    const float* row = adj + (size_t)n * N;
    int cnt = 0;
    for (int base = start; base < end; base += 256) {
        int m0 = base + 4 * lane;
        float4 v = make_float4(0.f, 0.f, 0.f, 0.f);
        if (m0 < end) v = *(const float4*)(row + m0);
#pragma unroll
        for (int c = 0; c < 4; c++) {
            float vc = (c == 0) ? v.x : (c == 1) ? v.y : (c == 2) ? v.z : v.w;
            bool p = vc > 0.5f;
            unsigned long long mask = __ballot(p);
            if (p) {
                int pos = cnt + __popcll(mask & ((1ull << lane) - 1ull));
                if (pos < 256) lbuf[w][pos] = (u16)(m0 + c);
            }
            cnt += __popcll(mask);
        }
    }
    if (cnt > 256) cnt = 256;
    if (lane == 0) wc[w] = cnt;
    __syncthreads();
    int offset = 0;
    for (int i = 0; i < w; i++) offset += wc[i];
    for (int i = lane; i < cnt; i += 64) {
        int idx = offset + i;
        if (idx < NBR_CAP) nbr[(size_t)n * NBR_CAP + idx] = lbuf[w][i];
    }
    if (t == 0) {
        int total = wc[0] + wc[1] + wc[2] + wc[3];
        ncnt[n] = total < NBR_CAP ? total : NBR_CAP;
    }
}

// K1: Wh = x @ W_heads (fp32), plus bf16 shadow Whb for the PV gather
__global__ void gemm_wh(const float* __restrict__ x,
                        const float* __restrict__ W,
                        float* __restrict__ Wh,
                        u16* __restrict__ Whb) {
    int h = blockIdx.y;
    int n0 = blockIdx.x * 64;
    __shared__ float xs[64][13];
    __shared__ float bs[12][128];
    int t = threadIdx.x;
    int tx = t & 31, ty = t >> 5;
    float acc[8][4] = {};
    for (int k0 = 0; k0 < FIN; k0 += 12) {
        for (int i = t; i < 64 * 12; i += 256) {
            int r = i / 12, c = i - r * 12;
            int n = n0 + r;
            xs[r][c] = (n < N) ? x[(size_t)n * FIN + k0 + c] : 0.f;
        }
        for (int i = t; i < 12 * 128; i += 256) {
            int r = i >> 7, c = i & 127;
            bs[r][c] = W[((size_t)h * FIN + (k0 + r)) * HID + c];
        }
        __syncthreads();
#pragma unroll
        for (int kk = 0; kk < 12; kk++) {
            float b[4];
#pragma unroll
            for (int j = 0; j < 4; j++) b[j] = bs[kk][tx * 4 + j];
#pragma unroll
            for (int i = 0; i < 8; i++) {
                float a = xs[ty * 8 + i][kk];
#pragma unroll
                for (int j = 0; j < 4; j++) acc[i][j] += a * b[j];
            }
        }
        __syncthreads();
    }
    for (int i = 0; i < 8; i++) {
        int n = n0 + ty * 8 + i;
        if (n < N) {
            size_t ro = ((size_t)h * N + n) * HID + tx * 4;
            float* o = Wh + ro;
#pragma unroll
            for (int j = 0; j < 4; j++) o[j] = acc[i][j];
            ushort4 b4;
            b4.x = f2bf(acc[i][0]); b4.y = f2bf(acc[i][1]);
            b4.z = f2bf(acc[i][2]); b4.w = f2bf(acc[i][3]);
            *(ushort4*)(Whb + ro) = b4;
        }
    }
}

// K2: f1/f2 per (h,n); one wave per pair (fp32 Wh)
__global__ void calc_f(const float* __restrict__ Wh,
                       const float* __restrict__ a_heads,
                       float* __restrict__ f1, float* __restrict__ f2) {
    int t = threadIdx.x, lane = t & 63, w = t >> 6;
    int pid = blockIdx.x * 4 + w;
    int h = pid / N, n = pid - h * N;
    const float* r = Wh + ((size_t)h * N + n) * HID;
    const float* a = a_heads + (size_t)h * 2 * HID;
    float v0 = r[lane], v1 = r[64 + lane];
    float s1 = v0 * a[lane] + v1 * a[64 + lane];
    float s2 = v0 * a[128 + lane] + v1 * a[192 + lane];
    for (int d = 32; d; d >>= 1) { s1 += __shfl_xor(s1, d); s2 += __shfl_xor(s2, d); }
    if (lane == 0) { f1[h * N + n] = s1; f2[h * N + n] = s2; }
}

// K3: layer-1 fused masked-softmax + PV, per-head blocks (head-major).
// 16 streams x 16 lanes x 8 cols; {w, byteoff} packed as float2 in LDS;
// hi-bf16 reinterpreted directly (lo bits = harmless mantissa extension).
__global__ void gat1(const u16* __restrict__ Whb,
                     const float* __restrict__ f1, const float* __restrict__ f2,
                     const u16* __restrict__ nbr,
                     const int* __restrict__ ncnt,
                     float* __restrict__ hcat) {
    int bid = blockIdx.x;
    int h = bid / N, n = bid - h * N;
    int t = threadIdx.x;
    int s = t >> 4, op = t & 15;
    int cnt = ncnt[n];
    const u16* lst = nbr + (size_t)n * NBR_CAP;
    __shared__ float2 wm[NBR_CAP];        // {weight, byte-offset bits}
    __shared__ float accl[16][16][9];     // padded: kills reduce bank conflicts
    __shared__ float swl[16];

    float f1c = f1[h * N + n];
    for (int i = t; i < cnt; i += 256) {
        int m = lst[i];
        float z = f1c + f2[h * N + m];
        z = (z >= 0.f) ? z : ALPHA * z;
        wm[i] = make_float2(__expf(z), __uint_as_float((u32)m << 8));
    }
    __syncthreads();

    const char* base = (const char*)(Whb + (size_t)h * N * HID) + (op << 4);
    float acc[8] = {};
    float sw = 0.f;
    int j = s;
    for (; j + 16 < cnt; j += 32) {
        float2 p0 = wm[j];
        float2 p1 = wm[j + 16];
        const uint4 va = *(const uint4*)(base + __float_as_uint(p0.y));
        const uint4 vb = *(const uint4*)(base + __float_as_uint(p1.y));
        float w0 = p0.x, w1 = p1.x;
        acc[0] += w0 * __uint_as_float(va.x << 16);
        acc[1] += w0 * __uint_as_float(va.x);
        acc[2] += w0 * __uint_as_float(va.y << 16);
        acc[3] += w0 * __uint_as_float(va.y);
        acc[4] += w0 * __uint_as_float(va.z << 16);
        acc[5] += w0 * __uint_as_float(va.z);
        acc[6] += w0 * __uint_as_float(va.w << 16);
        acc[7] += w0 * __uint_as_float(va.w);
        acc[0] += w1 * __uint_as_float(vb.x << 16);
        acc[1] += w1 * __uint_as_float(vb.x);
        acc[2] += w1 * __uint_as_float(vb.y << 16);
        acc[3] += w1 * __uint_as_float(vb.y);
        acc[4] += w1 * __uint_as_float(vb.z << 16);
        acc[5] += w1 * __uint_as_float(vb.z);
        acc[6] += w1 * __uint_as_float(vb.w << 16);
        acc[7] += w1 * __uint_as_float(vb.w);
        sw += w0 + w1;
    }
    if (j < cnt) {
        float2 p0 = wm[j];
        const uint4 va = *(const uint4*)(base + __float_as_uint(p0.y));
        float w0 = p0.x;
        acc[0] += w0 * __uint_as_float(va.x << 16);
        acc[1] += w0 * __uint_as_float(va.x);
        acc[2] += w0 * __uint_as_float(va.y << 16);
        acc[3] += w0 * __uint_as_float(va.y);
        acc[4] += w0 * __uint_as_float(va.z << 16);
        acc[5] += w0 * __uint_as_float(va.z);
        acc[6] += w0 * __uint_as_float(va.w << 16);
        acc[7] += w0 * __uint_as_float(va.w);
        sw += w0;
    }
#pragma unroll
    for (int c = 0; c < 8; c++) accl[s][op][c] = acc[c];
    if (op == 0) swl[s] = sw;
    __syncthreads();

    if (t < 128) {
        int c = t;
        float r = 0.f;
#pragma unroll
        for (int k = 0; k < 16; k++) r += accl[k][c >> 3][c & 7];
        float swt = 0.f;
#pragma unroll
        for (int k = 0; k < 16; k++) swt += swl[k];
        r /= swt;
        r = (r > 0.f) ? r : expm1f(r);
        hcat[(size_t)n * (NH * HID) + h * HID + c] = r;
    }
}

// K4: Wh2 = hcat(6000x1024) @ W_out(1024x128), split-K over 8 slices of 128.
__global__ void gemm_out(const float* __restrict__ hcat,
                         const float* __restrict__ W_out,
                         float* __restrict__ partial) {
    int n0 = blockIdx.x * 64;
    int ks = blockIdx.y;
    __shared__ float xs[64][17];
    __shared__ float bs[16][128];
    int t = threadIdx.x;
    int tx = t & 31, ty = t >> 5;
    float acc[8][4] = {};
    int kbeg = ks * 128, kend = kbeg + 128;
    for (int k0 = kbeg; k0 < kend; k0 += 16) {
        for (int i = t; i < 64 * 16; i += 256) {
            int r = i >> 4, c = i & 15;
            int n = n0 + r;
            xs[r][c] = (n < N) ? hcat[(size_t)n * 1024 + k0 + c] : 0.f;
        }
        for (int i = t; i < 16 * 128; i += 256) {
            int r = i >> 7, c = i & 127;
            bs[r][c] = W_out[(size_t)(k0 + r) * HID + c];
        }
        __syncthreads();
#pragma unroll
        for (int kk = 0; kk < 16; kk++) {
            float b[4];
#pragma unroll
            for (int j = 0; j < 4; j++) b[j] = bs[kk][tx * 4 + j];
#pragma unroll
            for (int i = 0; i < 8; i++) {
                float a = xs[ty * 8 + i][kk];
#pragma unroll
                for (int j = 0; j < 4; j++) acc[i][j] += a * b[j];
            }
        }
        __syncthreads();
    }
    float* pout = partial + (size_t)ks * N * HID;
    for (int i = 0; i < 8; i++) {
        int n = n0 + ty * 8 + i;
        if (n < N) {
#pragma unroll
            for (int j = 0; j < 4; j++)
                pout[(size_t)n * HID + tx * 4 + j] = acc[i][j];
        }
    }
}

// K4b: Wh2 = sum over the 8 K-split partials (float4 vectorized)
__global__ void reduce_wh2(const float* __restrict__ partial,
                           float* __restrict__ Wh2) {
    int idx = blockIdx.x * 256 + threadIdx.x;      // float4 index
    const int tot4 = N * HID / 4;                  // 192000
    if (idx >= tot4) return;
    float4 v = *(const float4*)(partial + 4 * (size_t)idx);
#pragma unroll
    for (int s = 1; s < KSPLIT; s++) {
        const float4 q = *(const float4*)(partial + (size_t)s * N * HID + 4 * (size_t)idx);
        v.x += q.x; v.y += q.y; v.z += q.z; v.w += q.w;
    }
    *(float4*)(Wh2 + 4 * (size_t)idx) = v;
}

// K5: g1/g2
__global__ void calc_g(const float* __restrict__ Wh2,
                       const float* __restrict__ a_out,
                       float* __restrict__ g1, float* __restrict__ g2) {
    int t = threadIdx.x, lane = t & 63, w = t >> 6;
    int n = blockIdx.x * 4 + w;
    const float* r = Wh2 + (size_t)n * HID;
    float v0 = r[lane], v1 = r[64 + lane];
    float s1 = v0 * a_out[lane] + v1 * a_out[64 + lane];
    float s2 = v0 * a_out[128 + lane] + v1 * a_out[192 + lane];
    for (int d = 32; d; d >>= 1) { s1 += __shfl_xor(s1, d); s2 += __shfl_xor(s2, d); }
    if (lane == 0) { g1[n] = s1; g2[n] = s2; }
}

// K6: layer-2 fused masked-softmax + PV (fp32, feeds output directly)
// Same stream structure as gat1: 16 streams x 16 lanes x 8 cols (2x float4).
__global__ void gat2(const float* __restrict__ Wh2,
                     const float* __restrict__ g1, const float* __restrict__ g2,
                     const u16* __restrict__ nbr,
                     const int* __restrict__ ncnt,
                     float* __restrict__ out) {
    int n = blockIdx.x, t = threadIdx.x;
    int s = t >> 4, op = t & 15;
    int cnt = ncnt[n];
    const u16* lst = nbr + (size_t)n * NBR_CAP;
    __shared__ float2 wm[NBR_CAP];
    __shared__ float accl[16][16][9];
    __shared__ float swl[16];

    float g1c = g1[n];
    for (int i = t; i < cnt; i += 256) {
        int m = lst[i];
        float z = g1c + g2[m];
        z = (z >= 0.f) ? z : ALPHA * z;
        wm[i] = make_float2(__expf(z), __uint_as_float((u32)m << 9));
    }
    __syncthreads();

    const char* base = (const char*)Wh2 + (op << 5);
    float acc[8] = {};
    float sw = 0.f;
    int j = s;
    for (; j + 16 < cnt; j += 32) {
        float2 p0 = wm[j];
        float2 p1 = wm[j + 16];
        const float4 va0 = *(const float4*)(base + __float_as_uint(p0.y));
        const float4 va1 = *(const float4*)(base + __float_as_uint(p0.y) + 16);
        const float4 vb0 = *(const float4*)(base + __float_as_uint(p1.y));
        const float4 vb1 = *(const float4*)(base + __float_as_uint(p1.y) + 16);
        float w0 = p0.x, w1 = p1.x;
        acc[0] += w0 * va0.x; acc[1] += w0 * va0.y;
        acc[2] += w0 * va0.z; acc[3] += w0 * va0.w;
        acc[4] += w0 * va1.x; acc[5] += w0 * va1.y;
        acc[6] += w0 * va1.z; acc[7] += w0 * va1.w;
        acc[0] += w1 * vb0.x; acc[1] += w1 * vb0.y;
        acc[2] += w1 * vb0.z; acc[3] += w1 * vb0.w;
        acc[4] += w1 * vb1.x; acc[5] += w1 * vb1.y;
        acc[6] += w1 * vb1.z; acc[7] += w1 * vb1.w;
        sw += w0 + w1;
    }
    if (j < cnt) {
        float2 p0 = wm[j];
        const float4 va0 = *(const float4*)(base + __float_as_uint(p0.y));
        const float4 va1 = *(const float4*)(base + __float_as_uint(p0.y) + 16);
        float w0 = p0.x;
        acc[0] += w0 * va0.x; acc[1] += w0 * va0.y;
        acc[2] += w0 * va0.z; acc[3] += w0 * va0.w;
        acc[4] += w0 * va1.x; acc[5] += w0 * va1.y;
        acc[6] += w0 * va1.z; acc[7] += w0 * va1.w;
        sw += w0;
    }
#pragma unroll
    for (int c = 0; c < 8; c++) accl[s][op][c] = acc[c];
    if (op == 0) swl[s] = sw;
    __syncthreads();

    if (t < 128) {
        int c = t;
        float r = 0.f;
#pragma unroll
        for (int k = 0; k < 16; k++) r += accl[k][c >> 3][c & 7];
        float swt = 0.f;
#pragma unroll
        for (int k = 0; k < 16; k++) swt += swl[k];
        out[(size_t)n * HID + c] = r / swt;
    }
}

extern "C" void kernel_launch(void* const* d_in, const int* in_sizes, int n_in,
                              void* d_out, int out_size, void* d_ws, size_t ws_size,
                              hipStream_t stream) {
    const float* x       = (const float*)d_in[0];
    const float* adj     = (const float*)d_in[1];
    const float* W_heads = (const float*)d_in[2];
    const float* a_heads = (const float*)d_in[3];
    const float* W_out   = (const float*)d_in[4];
    const float* a_out   = (const float*)d_in[5];
    float* out = (float*)d_out;

    char* wsb = (char*)d_ws;
    size_t off = 0;
    auto alloc = [&](size_t bytes) {
        void* p = wsb + off;
        off += (bytes + 255) & ~(size_t)255;
        return p;
    };
    float* Wh   = (float*)alloc(sizeof(float) * (size_t)NH * N * HID);  // 24.576 MB
    u16*   Whb  = (u16*)  alloc(sizeof(u16)   * (size_t)NH * N * HID);
    float* hcat = (float*)alloc(sizeof(float) * (size_t)N * NH * HID);
    float* Wh2  = (float*)alloc(sizeof(float) * (size_t)N * HID);
    float* f1   = (float*)alloc(sizeof(float) * (size_t)NH * N);
    float* f2   = (float*)alloc(sizeof(float) * (size_t)NH * N);
    float* g1   = (float*)alloc(sizeof(float) * (size_t)N);
    float* g2   = (float*)alloc(sizeof(float) * (size_t)N);
    u16* nbr    = (u16*)  alloc(sizeof(u16)   * (size_t)N * NBR_CAP);
    int* ncnt   = (int*)  alloc(sizeof(int)   * (size_t)N);

    // partial[KSPLIT][N][HID] aliases Wh (same size; Wh's last reader calc_f
    // precedes gemm_out in stream order).
    float* partial = Wh;

    hipLaunchKernelGGL(build_nbr, dim3(N), dim3(256), 0, stream, adj, nbr, ncnt);
    hipLaunchKernelGGL(gemm_wh, dim3((N + 63) / 64, NH), dim3(256), 0, stream, x, W_heads, Wh, Whb);
    hipLaunchKernelGGL(calc_f, dim3(NH * N / 4), dim3(256), 0, stream, Wh, a_heads, f1, f2);
    hipLaunchKernelGGL(gat1, dim3(NH * N), dim3(256), 0, stream, Whb, f1, f2, nbr, ncnt, hcat);
    hipLaunchKernelGGL(gemm_out, dim3((N + 63) / 64, KSPLIT), dim3(256), 0, stream, hcat, W_out, partial);
    hipLaunchKernelGGL(reduce_wh2, dim3((N * HID / 4 + 255) / 256), dim3(256), 0, stream, partial, Wh2);
    hipLaunchKernelGGL(calc_g, dim3(N / 4), dim3(256), 0, stream, Wh2, a_out, g1, g2);
    hipLaunchKernelGGL(gat2, dim3(N), dim3(256), 0, stream, Wh2, g1, g2, nbr, ncnt, out);
}